// Round 7
// baseline (829.207 us; speedup 1.0000x reference)
//
#include <hip/hip_runtime.h>
#include <math.h>

// ConditionalCNF log_prob, MFMA version, round 7.
// Round-6 shape (32 rows/block, grid 512 = 2 blocks/CU, 256-reg budget) plus:
//  - trace identity: tr = e^T J e = dh2 . (W3 @ e); u = e@W3^T via MFMA reusing
//    the eps A-frags -> tangent h2 never converted/written to LDS, trace is
//    register FMAs, reduced once at kernel end (no per-stage shuffles/ebf).
//  - eps loaded direct into A-frag registers (no LDS roundtrip).
//  - t folded into layer-1 MFMA k=16 slot (B row 16 = W1[272], A k16 = ts).
//  - layer-3 + RK4 + Y staging on waves 2/3 (were idle); 3-term A&S erf.

#define DTc (-0.1f)

typedef __attribute__((ext_vector_type(8))) short bf16x8;
typedef __attribute__((ext_vector_type(8))) unsigned short u16x8;
typedef __attribute__((ext_vector_type(4))) float f32x4;

#define MFMA16(a, b, c) __builtin_amdgcn_mfma_f32_16x16x32_bf16((a), (b), (c), 0, 0, 0)

__device__ __forceinline__ unsigned short f2bf(float x) {
    union { float f; unsigned int u; } c; c.f = x;
    unsigned int r = c.u + 0x7FFFu + ((c.u >> 16) & 1u);   // RNE
    return (unsigned short)(r >> 16);
}

__device__ __forceinline__ unsigned int pk2bf(float lo, float hi) {
#if __has_builtin(__builtin_amdgcn_cvt_pk_bf16_f32)
    auto v = __builtin_amdgcn_cvt_pk_bf16_f32(lo, hi);     // v_cvt_pk_bf16_f32 (RNE)
    return __builtin_bit_cast(unsigned int, v);
#else
    return (unsigned int)f2bf(lo) | ((unsigned int)f2bf(hi) << 16);
#endif
}

// exact-GELU (erf) + derivative via A&S 7.1.25 3-term rational erf, sharing
// exp(-x^2/2) with the pdf. |erf err| <= 2.5e-5 << bf16 activation rounding.
__device__ __forceinline__ void gelu_both(float x, float& gv, float& dv) {
    float z  = fabsf(x) * 0.70710678118654752f;
    float e  = __builtin_amdgcn_exp2f(x * x * -0.72134752044448170f);  // exp(-x^2/2)
    float t  = __builtin_amdgcn_rcpf(__builtin_fmaf(0.47047f, z, 1.0f));
    float p  = t * (0.1740121f + t * (-0.0479399f + t * 0.3739278f));  // 0.5*(a1 t+a2 t^2+a3 t^3)
    float ch = p * e;                                                  // 0.5*erfc(z)
    float cdf = (x >= 0.0f) ? (1.0f - ch) : ch;
    gv = x * cdf;
    dv = __builtin_fmaf(0.39894228040143268f * x, e, cdf);
}

// ---------------- weight repack: fp32 -> bf16 B-fragments in ws ----------------
// w2f : [kb(6)][nt(12)][lane(64)][8]   B[n][k]=W2[k][n]
// w1yf: [nt(12)][lane(64)][8]          k<16 -> W1[k][n]; k==16 -> W1[272][n]; else 0
// w1cf: [kb(8)][nt(12)][lane(64)][8]   B[n][k]=W1[16+k][n]
// w3f : [kb(6)][lane(64)][8]           B[n][k]=W3[k][n], n=lane&15 (d)
// w3tf: [nt(12)][lane(64)][8]          B[n=hid][k=d] = W3[hid][d]; k>=16 -> 0
__global__ void repack_kernel(const float* __restrict__ W1, const float* __restrict__ W2,
                              const float* __restrict__ W3,
                              unsigned short* __restrict__ w2f, unsigned short* __restrict__ w1yf,
                              unsigned short* __restrict__ w1cf, unsigned short* __restrict__ w3fg,
                              unsigned short* __restrict__ w3tf) {
    int t = blockIdx.x * 256 + threadIdx.x;
    u16x8 v;
    if (t < 4608) {
        int kb = t / 768, rem = t % 768, nt = rem / 64, lane = rem % 64;
        int n = nt * 16 + (lane & 15), k0 = kb * 32 + (lane >> 4) * 8;
        #pragma unroll
        for (int j = 0; j < 8; ++j) v[j] = f2bf(W2[(k0 + j) * 192 + n]);
        *(u16x8*)(w2f + t * 8) = v;
    } else if (t < 5376) {
        int i2 = t - 4608, nt = i2 / 64, lane = i2 % 64;
        int n = nt * 16 + (lane & 15), k0 = (lane >> 4) * 8;
        #pragma unroll
        for (int j = 0; j < 8; ++j) {
            int k = k0 + j;
            v[j] = (k < 16) ? f2bf(W1[k * 192 + n])
                 : (k == 16) ? f2bf(W1[272 * 192 + n]) : (unsigned short)0;
        }
        *(u16x8*)(w1yf + i2 * 8) = v;
    } else if (t < 11520) {
        int i3 = t - 5376, kb = i3 / 768, rem = i3 % 768, nt = rem / 64, lane = rem % 64;
        int n = nt * 16 + (lane & 15), k0 = kb * 32 + (lane >> 4) * 8;
        #pragma unroll
        for (int j = 0; j < 8; ++j) v[j] = f2bf(W1[(16 + k0 + j) * 192 + n]);
        *(u16x8*)(w1cf + i3 * 8) = v;
    } else if (t < 11904) {
        int i4 = t - 11520, kb = i4 / 64, lane = i4 % 64;
        int n = lane & 15, k0 = kb * 32 + (lane >> 4) * 8;
        #pragma unroll
        for (int j = 0; j < 8; ++j) v[j] = f2bf(W3[(k0 + j) * 16 + n]);
        *(u16x8*)(w3fg + i4 * 8) = v;
    } else if (t < 12672) {
        int i5 = t - 11904, nt = i5 / 64, lane = i5 % 64;
        int h = nt * 16 + (lane & 15), quad = lane >> 4;
        #pragma unroll
        for (int j = 0; j < 8; ++j) {
            int d = quad * 8 + j;
            v[j] = (d < 16) ? f2bf(W3[h * 16 + d]) : (unsigned short)0;
        }
        *(u16x8*)(w3tf + i5 * 8) = v;
    }
}

// ---------------- main kernel ----------------
__global__ __launch_bounds__(256, 2) void cnf_mfma(
    const float* __restrict__ theta, const float* __restrict__ hctx,
    const float* __restrict__ eps,   const float* __restrict__ b1,
    const float* __restrict__ b2,    const float* __restrict__ b3,
    const unsigned short* __restrict__ w2f, const unsigned short* __restrict__ w1yf,
    const unsigned short* __restrict__ w1cf, const unsigned short* __restrict__ w3fg,
    const unsigned short* __restrict__ w3tf,
    float* __restrict__ out)
{
    __shared__ __align__(16) unsigned short Ys[32 * 24];   // fwd y rows, k 0-15 (stride 24 for align+banks)
    __shared__ __align__(16) unsigned short Xa0[64 * 200]; // h1/dh1 (aliased as Hs at init)
    __shared__ __align__(16) unsigned short Xa1[32 * 200]; // h2 (fwd rows only)
    __shared__ float trrow[32];

    const int tid  = threadIdx.x;
    const int wave = tid >> 6, lane = tid & 63;
    const int l15  = lane & 15, quad = lane >> 4;
    const int r0   = blockIdx.x * 32;
    const int ntg0 = wave * 3;
    const int mt3  = wave - 2;      // layer-3/RK4 m-tile for waves 2,3

    if (tid < 32) trrow[tid] = 0.0f;

    // stage h -> Hs (alias Xa0), stride 264 bf16, float4 global reads
    unsigned short* Hs = Xa0;
    for (int t4 = tid; t4 < 2048; t4 += 256) {
        int r = t4 >> 6, k = (t4 & 63) * 4;
        float4 v = *(const float4*)(hctx + (long)(r0 + r) * 256 + k);
        *(uint2*)(&Hs[r * 264 + k]) = make_uint2(pk2bf(v.x, v.y), pk2bf(v.z, v.w));
    }

    // per-wave constant fragments / scalars
    bf16x8 b1yfr[3], w3fr[6];
    #pragma unroll
    for (int nt = 0; nt < 3; ++nt)
        b1yfr[nt] = *reinterpret_cast<const bf16x8*>(w1yf + ((ntg0 + nt) * 64 + lane) * 8);
    if (wave >= 2) {
        #pragma unroll
        for (int kb = 0; kb < 6; ++kb)
            w3fr[kb] = *reinterpret_cast<const bf16x8*>(w3fg + (kb * 64 + lane) * 8);
    }
    float b2r[3], b1r[3];
    #pragma unroll
    for (int nt = 0; nt < 3; ++nt) {
        int n = (ntg0 + nt) * 16 + l15;
        b2r[nt] = b2[n];
        b1r[nt] = b1[n];
    }
    const float b3r = b3[l15];

    // waves 2,3: integration state yreg[i] = y[r = mt3*16+quad*4+i][d = l15]
    float yreg[4];
    if (wave >= 2) {
        #pragma unroll
        for (int i = 0; i < 4; ++i)
            yreg[i] = theta[(r0 + mt3 * 16 + quad * 4 + i) * 16 + l15];
    }

    // eps A-frags for sg=0: lane (l15, quad<2) holds e[r0+16mt+l15][quad*8..+7]
    bf16x8 e0 = {}, e1 = {};
    if (quad < 2) {
        const float* ep = eps + ((long)r0 + l15) * 16 + quad * 8;
        float4 a0 = *(const float4*)ep,          a1 = *(const float4*)(ep + 4);
        float4 b0 = *(const float4*)(ep + 256),  b4 = *(const float4*)(ep + 260);
        union { unsigned int u[4]; bf16x8 v; } c0, c1;
        c0.u[0] = pk2bf(a0.x, a0.y); c0.u[1] = pk2bf(a0.z, a0.w);
        c0.u[2] = pk2bf(a1.x, a1.y); c0.u[3] = pk2bf(a1.z, a1.w);
        c1.u[0] = pk2bf(b0.x, b0.y); c1.u[1] = pk2bf(b0.z, b0.w);
        c1.u[2] = pk2bf(b4.x, b4.y); c1.u[3] = pk2bf(b4.z, b4.w);
        e0 = c0.v; e1 = c1.v;
    }

    __syncthreads();   // Hs visible

    // ---- c = b1 + h @ W1ctx, in registers (fwd rows, mt 0-1) ----
    float cr[2][3][4];
    {
        f32x4 ca[2][3] = {};
        #pragma unroll
        for (int kb = 0; kb < 8; ++kb) {
            bf16x8 af[2];
            #pragma unroll
            for (int mt = 0; mt < 2; ++mt)
                af[mt] = *reinterpret_cast<const bf16x8*>(&Hs[(mt * 16 + l15) * 264 + kb * 32 + quad * 8]);
            #pragma unroll
            for (int nt = 0; nt < 3; ++nt) {
                bf16x8 bf = *reinterpret_cast<const bf16x8*>(w1cf + ((kb * 12 + ntg0 + nt) * 64 + lane) * 8);
                #pragma unroll
                for (int mt = 0; mt < 2; ++mt)
                    ca[mt][nt] = MFMA16(af[mt], bf, ca[mt][nt]);
            }
        }
        #pragma unroll
        for (int mt = 0; mt < 2; ++mt)
            #pragma unroll
            for (int nt = 0; nt < 3; ++nt)
                #pragma unroll
                for (int i = 0; i < 4; ++i)
                    cr[mt][nt][i] = ca[mt][nt][i] + b1r[nt];
    }

    // initial Y staging (waves 2,3 own fwd rows)
    if (wave >= 2) {
        #pragma unroll
        for (int i = 0; i < 4; ++i)
            Ys[(mt3 * 16 + quad * 4 + i) * 24 + l15] = f2bf(yreg[i]);
    }

    float F1[4], F2[4], F3[4];
    float tracc[2][4] = {{0.f,0.f,0.f,0.f},{0.f,0.f,0.f,0.f}};

    for (int sg = 0; sg < 40; ++sg) {
        const int sub = sg & 3;
        const float ts = 1.0f + DTc * (float)(sg >> 2) + DTc * ((float)sub * (1.0f / 3.0f));
        const short tsb = (short)f2bf(ts);

        __syncthreads();   // B1: Y staged, prev Xa0 reads done

        // ---- A-frags for y rows: quads 0,1 from Ys; quad 2 lane j0 = ts (k=16 slot) ----
        bf16x8 aY0 = {}, aY1 = {};
        if (quad < 2) {
            aY0 = *reinterpret_cast<const bf16x8*>(&Ys[l15 * 24 + quad * 8]);
            aY1 = *reinterpret_cast<const bf16x8*>(&Ys[(16 + l15) * 24 + quad * 8]);
        } else if (quad == 2) {
            aY0[0] = tsb; aY1[0] = tsb;
        }

        // ---- u = e @ W3^T (for trace) and layer 1, interleaved ----
        f32x4 uacc[2][3] = {};
        f32x4 acc[4][3]  = {};
        #pragma unroll
        for (int nt = 0; nt < 3; ++nt) {
            bf16x8 w3t = *reinterpret_cast<const bf16x8*>(w3tf + ((ntg0 + nt) * 64 + lane) * 8);
            uacc[0][nt] = MFMA16(e0, w3t, uacc[0][nt]);
            uacc[1][nt] = MFMA16(e1, w3t, uacc[1][nt]);
            acc[0][nt] = MFMA16(aY0, b1yfr[nt], acc[0][nt]);
            acc[1][nt] = MFMA16(aY1, b1yfr[nt], acc[1][nt]);
            acc[2][nt] = MFMA16(e0,  b1yfr[nt], acc[2][nt]);
            acc[3][nt] = MFMA16(e1,  b1yfr[nt], acc[3][nt]);
        }

        // ---- prefetch next-stage eps (registers; converted post-B3) ----
        float4 pa0, pa1, pb0, pb1;
        if (sg < 39 && quad < 2) {
            const float* ep = eps + ((long)(sg + 1) * 16384 + r0 + l15) * 16 + quad * 8;
            pa0 = *(const float4*)ep;         pa1 = *(const float4*)(ep + 4);
            pb0 = *(const float4*)(ep + 256); pb1 = *(const float4*)(ep + 260);
        }

        // ---- layer 1 epilogue: GELU -> Xa0 (fwd h1 + tangent dh1) ----
        #pragma unroll
        for (int nt = 0; nt < 3; ++nt) {
            int n = (ntg0 + nt) * 16 + l15;
            #pragma unroll
            for (int mt = 0; mt < 2; ++mt) {
                float gvv[4], dvv[4];
                #pragma unroll
                for (int i = 0; i < 4; ++i) {
                    float a = acc[mt][nt][i] + cr[mt][nt][i];
                    float gv, dv; gelu_both(a, gv, dv);
                    gvv[i] = gv; dvv[i] = dv * acc[mt + 2][nt][i];
                }
                unsigned int p0 = pk2bf(gvv[0], gvv[1]), p1 = pk2bf(gvv[2], gvv[3]);
                unsigned int q0 = pk2bf(dvv[0], dvv[1]), q1 = pk2bf(dvv[2], dvv[3]);
                int ba = (mt * 16 + quad * 4) * 200 + n;
                Xa0[ba]          = (unsigned short)p0;
                Xa0[ba + 200]    = (unsigned short)(p0 >> 16);
                Xa0[ba + 400]    = (unsigned short)p1;
                Xa0[ba + 600]    = (unsigned short)(p1 >> 16);
                Xa0[ba + 6400]   = (unsigned short)q0;
                Xa0[ba + 6600]   = (unsigned short)(q0 >> 16);
                Xa0[ba + 6800]   = (unsigned short)q1;
                Xa0[ba + 7000]   = (unsigned short)(q1 >> 16);
            }
        }
        __syncthreads();   // B2: Xa0 ready

        // ---- layer 2 (K=192) ----
        f32x4 acc2[4][3] = {};
        #pragma unroll
        for (int kb = 0; kb < 6; ++kb) {
            bf16x8 aA[4];
            #pragma unroll
            for (int mt = 0; mt < 4; ++mt)
                aA[mt] = *reinterpret_cast<const bf16x8*>(&Xa0[(mt * 16 + l15) * 200 + kb * 32 + quad * 8]);
            #pragma unroll
            for (int nt = 0; nt < 3; ++nt) {
                bf16x8 bf = *reinterpret_cast<const bf16x8*>(w2f + ((kb * 12 + ntg0 + nt) * 64 + lane) * 8);
                #pragma unroll
                for (int mt = 0; mt < 4; ++mt)
                    acc2[mt][nt] = MFMA16(aA[mt], bf, acc2[mt][nt]);
            }
        }

        // ---- layer 2 epilogue: fwd h2 -> Xa1; tangent dh2 -> trace FMA vs u ----
        {
            float tsum[2][4] = {{0.f,0.f,0.f,0.f},{0.f,0.f,0.f,0.f}};
            #pragma unroll
            for (int nt = 0; nt < 3; ++nt) {
                int n = (ntg0 + nt) * 16 + l15;
                #pragma unroll
                for (int mt = 0; mt < 2; ++mt) {
                    float gvv[4];
                    #pragma unroll
                    for (int i = 0; i < 4; ++i) {
                        float a = acc2[mt][nt][i] + b2r[nt];
                        float gv, dv; gelu_both(a, gv, dv);
                        gvv[i] = gv;
                        float dh2 = dv * acc2[mt + 2][nt][i];
                        tsum[mt][i] = __builtin_fmaf(dh2, uacc[mt][nt][i], tsum[mt][i]);
                    }
                    unsigned int p0 = pk2bf(gvv[0], gvv[1]), p1 = pk2bf(gvv[2], gvv[3]);
                    int ba = (mt * 16 + quad * 4) * 200 + n;
                    Xa1[ba]       = (unsigned short)p0;
                    Xa1[ba + 200] = (unsigned short)(p0 >> 16);
                    Xa1[ba + 400] = (unsigned short)p1;
                    Xa1[ba + 600] = (unsigned short)(p1 >> 16);
                }
            }
            const float csub = (sub == 1 || sub == 2) ? 3.0f : 1.0f;
            #pragma unroll
            for (int mt = 0; mt < 2; ++mt)
                #pragma unroll
                for (int i = 0; i < 4; ++i)
                    tracc[mt][i] = __builtin_fmaf(csub, tsum[mt][i], tracc[mt][i]);
        }
        __syncthreads();   // B3: Xa1 ready

        // ---- layer 3 + RK4 + Y staging on waves 2,3 ----
        if (wave >= 2) {
            f32x4 acc3 = {};
            const unsigned short* src = &Xa1[(mt3 * 16 + l15) * 200];
            #pragma unroll
            for (int kb = 0; kb < 6; ++kb)
                acc3 = MFMA16(*reinterpret_cast<const bf16x8*>(src + kb * 32 + quad * 8), w3fr[kb], acc3);
            float Fc[4];
            #pragma unroll
            for (int i = 0; i < 4; ++i) Fc[i] = acc3[i] + b3r;
            if (sub == 0) {
                #pragma unroll
                for (int i = 0; i < 4; ++i) F1[i] = Fc[i];
            } else if (sub == 1) {
                #pragma unroll
                for (int i = 0; i < 4; ++i) F2[i] = Fc[i];
            } else if (sub == 2) {
                #pragma unroll
                for (int i = 0; i < 4; ++i) F3[i] = Fc[i];
            } else {
                #pragma unroll
                for (int i = 0; i < 4; ++i)
                    yreg[i] += DTc * 0.125f * (F1[i] + 3.0f * (F2[i] + F3[i]) + Fc[i]);
            }
            if (sg < 39) {
                const int sub2 = (sg + 1) & 3;
                #pragma unroll
                for (int i = 0; i < 4; ++i) {
                    float ys = yreg[i];
                    if (sub2 == 1)      ys += DTc * (1.0f / 3.0f) * F1[i];
                    else if (sub2 == 2) ys += DTc * (F2[i] - (1.0f / 3.0f) * F1[i]);
                    else if (sub2 == 3) ys += DTc * (F1[i] - F2[i] + F3[i]);
                    Ys[(mt3 * 16 + quad * 4 + i) * 24 + l15] = f2bf(ys);
                }
            }
        }

        // ---- convert prefetched eps to A-frags for next stage ----
        if (sg < 39) {
            e0 = bf16x8{}; e1 = bf16x8{};
            if (quad < 2) {
                union { unsigned int u[4]; bf16x8 v; } c0, c1;
                c0.u[0] = pk2bf(pa0.x, pa0.y); c0.u[1] = pk2bf(pa0.z, pa0.w);
                c0.u[2] = pk2bf(pa1.x, pa1.y); c0.u[3] = pk2bf(pa1.z, pa1.w);
                c1.u[0] = pk2bf(pb0.x, pb0.y); c1.u[1] = pk2bf(pb0.z, pb0.w);
                c1.u[2] = pk2bf(pb1.x, pb1.y); c1.u[3] = pk2bf(pb1.z, pb1.w);
                e0 = c0.v; e1 = c1.v;
            }
        }
    }

    // ---- final trace reduction: shuffle over l15, cross-wave via LDS atomics ----
    #pragma unroll
    for (int mt = 0; mt < 2; ++mt)
        #pragma unroll
        for (int i = 0; i < 4; ++i) {
            float v = tracc[mt][i];
            v += __shfl_xor(v, 1);
            v += __shfl_xor(v, 2);
            v += __shfl_xor(v, 4);
            v += __shfl_xor(v, 8);
            if (l15 == 0) atomicAdd(&trrow[mt * 16 + quad * 4 + i], v);
        }
    __syncthreads();

    // ---- output (waves 2,3 hold final y) ----
    if (wave >= 2) {
        #pragma unroll
        for (int i = 0; i < 4; ++i) {
            float q = yreg[i] * yreg[i];
            q += __shfl_xor(q, 1);
            q += __shfl_xor(q, 2);
            q += __shfl_xor(q, 4);
            q += __shfl_xor(q, 8);
            if (l15 == 0) {
                int r = mt3 * 16 + quad * 4 + i;
                out[r0 + r] = -0.5f * q - 14.7030165313f + DTc * 0.125f * trrow[r];
            }
        }
    }
}

extern "C" void kernel_launch(void* const* d_in, const int* in_sizes, int n_in,
                              void* d_out, int out_size, void* d_ws, size_t ws_size,
                              hipStream_t stream) {
    const float* theta = (const float*)d_in[0];
    const float* hctx  = (const float*)d_in[1];
    const float* eps   = (const float*)d_in[2];
    const float* W1    = (const float*)d_in[3];
    const float* b1    = (const float*)d_in[4];
    const float* W2    = (const float*)d_in[5];
    const float* b2    = (const float*)d_in[6];
    const float* W3    = (const float*)d_in[7];
    const float* b3    = (const float*)d_in[8];
    float* outp = (float*)d_out;

    unsigned short* w2f  = (unsigned short*)d_ws;   // 36864 elems
    unsigned short* w1yf = w2f + 36864;             // 6144
    unsigned short* w1cf = w1yf + 6144;             // 49152
    unsigned short* w3fg = w1cf + 49152;            // 3072
    unsigned short* w3tf = w3fg + 3072;             // 6144

    hipLaunchKernelGGL(repack_kernel, dim3(50), dim3(256), 0, stream,
                       W1, W2, W3, w2f, w1yf, w1cf, w3fg, w3tf);
    hipLaunchKernelGGL(cnf_mfma, dim3(512), dim3(256), 0, stream,
                       theta, hctx, eps, b1, b2, b3, w2f, w1yf, w1cf, w3fg, w3tf, outp);
}

// Round 8
// 380.953 us; speedup vs baseline: 2.1767x; 2.1767x over previous
//
#include <hip/hip_runtime.h>
#include <math.h>

// ConditionalCNF log_prob, MFMA version, round 8.
// Round-6 base (32 rows/block, grid 512 = 2 blocks/CU, 256-reg budget, no spill)
// + pressure-neutral cuts: t folded into layer-1 MFMA k16 slot (B row16=W1[272]),
// Y buffer shrunk to k0..15 (quads 2/3 register-synthesized), 3-term A&S erf.

#define DTc (-0.1f)

typedef __attribute__((ext_vector_type(8))) short bf16x8;
typedef __attribute__((ext_vector_type(8))) unsigned short u16x8;
typedef __attribute__((ext_vector_type(4))) float f32x4;

#define MFMA16(a, b, c) __builtin_amdgcn_mfma_f32_16x16x32_bf16((a), (b), (c), 0, 0, 0)

__device__ __forceinline__ unsigned short f2bf(float x) {
    union { float f; unsigned int u; } c; c.f = x;
    unsigned int r = c.u + 0x7FFFu + ((c.u >> 16) & 1u);   // RNE
    return (unsigned short)(r >> 16);
}

__device__ __forceinline__ unsigned int pk2bf(float lo, float hi) {
#if __has_builtin(__builtin_amdgcn_cvt_pk_bf16_f32)
    auto v = __builtin_amdgcn_cvt_pk_bf16_f32(lo, hi);     // v_cvt_pk_bf16_f32 (RNE)
    return __builtin_bit_cast(unsigned int, v);
#else
    return (unsigned int)f2bf(lo) | ((unsigned int)f2bf(hi) << 16);
#endif
}

// exact-GELU (erf) + derivative via A&S 7.1.25 3-term rational erf, sharing
// exp(-x^2/2) with the pdf. |erf err| <= 2.5e-5 << bf16 activation rounding.
__device__ __forceinline__ void gelu_both(float x, float& gv, float& dv) {
    float z  = fabsf(x) * 0.70710678118654752f;
    float e  = __builtin_amdgcn_exp2f(x * x * -0.72134752044448170f);  // exp(-x^2/2)
    float t  = __builtin_amdgcn_rcpf(__builtin_fmaf(0.47047f, z, 1.0f));
    float p  = t * (0.1740121f + t * (-0.0479399f + t * 0.3739278f));  // 0.5*(a1 t+a2 t^2+a3 t^3)
    float ch = p * e;                                                  // 0.5*erfc(z)
    float cdf = (x >= 0.0f) ? (1.0f - ch) : ch;
    gv = x * cdf;
    dv = __builtin_fmaf(0.39894228040143268f * x, e, cdf);
}

// ---------------- weight repack: fp32 -> bf16 B-fragments in ws ----------------
// w2f : [kb(6)][nt(12)][lane(64)][8]   B[n][k]=W2[k][n]
// w1yf: [nt(12)][lane(64)][8]          k<16 -> W1[k][n]; k==16 -> W1[272][n]; else 0
// w1cf: [kb(8)][nt(12)][lane(64)][8]   B[n][k]=W1[16+k][n]
// w3f : [kb(6)][lane(64)][8]           B[n][k]=W3[k][n], n=lane&15 (d)
__global__ void repack_kernel(const float* __restrict__ W1, const float* __restrict__ W2,
                              const float* __restrict__ W3,
                              unsigned short* __restrict__ w2f, unsigned short* __restrict__ w1yf,
                              unsigned short* __restrict__ w1cf, unsigned short* __restrict__ w3fg) {
    int t = blockIdx.x * 256 + threadIdx.x;
    u16x8 v;
    if (t < 4608) {
        int kb = t / 768, rem = t % 768, nt = rem / 64, lane = rem % 64;
        int n = nt * 16 + (lane & 15), k0 = kb * 32 + (lane >> 4) * 8;
        #pragma unroll
        for (int j = 0; j < 8; ++j) v[j] = f2bf(W2[(k0 + j) * 192 + n]);
        *(u16x8*)(w2f + t * 8) = v;
    } else if (t < 5376) {
        int i2 = t - 4608, nt = i2 / 64, lane = i2 % 64;
        int n = nt * 16 + (lane & 15), k0 = (lane >> 4) * 8;
        #pragma unroll
        for (int j = 0; j < 8; ++j) {
            int k = k0 + j;
            v[j] = (k < 16) ? f2bf(W1[k * 192 + n])
                 : (k == 16) ? f2bf(W1[272 * 192 + n]) : (unsigned short)0;
        }
        *(u16x8*)(w1yf + i2 * 8) = v;
    } else if (t < 11520) {
        int i3 = t - 5376, kb = i3 / 768, rem = i3 % 768, nt = rem / 64, lane = rem % 64;
        int n = nt * 16 + (lane & 15), k0 = kb * 32 + (lane >> 4) * 8;
        #pragma unroll
        for (int j = 0; j < 8; ++j) v[j] = f2bf(W1[(16 + k0 + j) * 192 + n]);
        *(u16x8*)(w1cf + i3 * 8) = v;
    } else if (t < 11904) {
        int i4 = t - 11520, kb = i4 / 64, lane = i4 % 64;
        int n = lane & 15, k0 = kb * 32 + (lane >> 4) * 8;
        #pragma unroll
        for (int j = 0; j < 8; ++j) v[j] = f2bf(W3[(k0 + j) * 16 + n]);
        *(u16x8*)(w3fg + i4 * 8) = v;
    }
}

// ---------------- main kernel ----------------
__global__ __launch_bounds__(256, 2) void cnf_mfma(
    const float* __restrict__ theta, const float* __restrict__ hctx,
    const float* __restrict__ eps,   const float* __restrict__ b1,
    const float* __restrict__ b2,    const float* __restrict__ b3,
    const unsigned short* __restrict__ w2f, const unsigned short* __restrict__ w1yf,
    const unsigned short* __restrict__ w1cf, const unsigned short* __restrict__ w3fg,
    float* __restrict__ out)
{
    __shared__ __align__(16) unsigned short Ys[64 * 24];   // rows 0-31 y, 32-63 e; k 0..15 only
    __shared__ __align__(16) unsigned short Xa0[64 * 200]; // h1/dh1 (aliased as Hs at init)
    __shared__ __align__(16) unsigned short Xa1[64 * 200]; // h2/dh2
    __shared__ __align__(16) float ebf[2][512];            // fp32 eps, double-buffered
    __shared__ float trx[32];

    const int tid  = threadIdx.x;
    const int wave = tid >> 6, lane = tid & 63;
    const int l15  = lane & 15, quad = lane >> 4;
    const int r0   = blockIdx.x * 32;
    const int ntg0 = wave * 3;

    // stage h -> Hs (alias Xa0), stride 264 bf16, float4 global reads
    unsigned short* Hs = Xa0;
    for (int t4 = tid; t4 < 2048; t4 += 256) {
        int r = t4 >> 6, k = (t4 & 63) * 4;
        float4 v = *(const float4*)(hctx + (long)(r0 + r) * 256 + k);
        *(uint2*)(&Hs[r * 264 + k]) = make_uint2(pk2bf(v.x, v.y), pk2bf(v.z, v.w));
    }

    // eps register prefetch (waves 2,3): 4 elems/lane, float4 coalesced
    const int  ek = ((wave - 2) * 64 + lane) * 4;          // 0..508, valid for wave>=2
    const int  er = ek >> 4, ed = ek & 15;
    const long epsBase = (long)r0 * 16 + ek;
    float4 epr;
    if (wave >= 2) epr = *(const float4*)(eps + epsBase);  // sg = 0

    // per-wave constant fragments / scalars
    bf16x8 b1yfr[3], w3fr[6];
    #pragma unroll
    for (int nt = 0; nt < 3; ++nt)
        b1yfr[nt] = *reinterpret_cast<const bf16x8*>(w1yf + ((ntg0 + nt) * 64 + lane) * 8);
    #pragma unroll
    for (int kb = 0; kb < 6; ++kb)
        w3fr[kb] = *reinterpret_cast<const bf16x8*>(w3fg + (kb * 64 + lane) * 8);
    float b2r[3], b1r[3];
    #pragma unroll
    for (int nt = 0; nt < 3; ++nt) {
        int n = (ntg0 + nt) * 16 + l15;
        b2r[nt] = b2[n];
        b1r[nt] = b1[n];
    }
    const float b3r = b3[l15];

    // wave 0 integration state: yreg[mt][i] = y[r = mt*16+quad*4+i][d = l15]
    float yreg[2][4];
    if (wave == 0) {
        #pragma unroll
        for (int mt = 0; mt < 2; ++mt)
            #pragma unroll
            for (int i = 0; i < 4; ++i)
                yreg[mt][i] = theta[(r0 + mt * 16 + quad * 4 + i) * 16 + l15];
    }

    __syncthreads();   // Hs visible

    // ---- c = b1 + h @ W1ctx, in registers (fwd rows only, mt 0-1) ----
    float cr[2][3][4];
    {
        f32x4 ca[2][3] = {};
        #pragma unroll
        for (int kb = 0; kb < 8; ++kb) {
            bf16x8 af[2];
            #pragma unroll
            for (int mt = 0; mt < 2; ++mt)
                af[mt] = *reinterpret_cast<const bf16x8*>(&Hs[(mt * 16 + l15) * 264 + kb * 32 + quad * 8]);
            #pragma unroll
            for (int nt = 0; nt < 3; ++nt) {
                bf16x8 bf = *reinterpret_cast<const bf16x8*>(w1cf + ((kb * 12 + ntg0 + nt) * 64 + lane) * 8);
                #pragma unroll
                for (int mt = 0; mt < 2; ++mt)
                    ca[mt][nt] = MFMA16(af[mt], bf, ca[mt][nt]);
            }
        }
        #pragma unroll
        for (int mt = 0; mt < 2; ++mt)
            #pragma unroll
            for (int nt = 0; nt < 3; ++nt)
                #pragma unroll
                for (int i = 0; i < 4; ++i)
                    cr[mt][nt][i] = ca[mt][nt][i] + b1r[nt];
    }

    // ---- initial staging for sg=0 ----
    if (wave == 0) {
        #pragma unroll
        for (int mt = 0; mt < 2; ++mt)
            #pragma unroll
            for (int i = 0; i < 4; ++i)
                Ys[(mt * 16 + quad * 4 + i) * 24 + l15] = f2bf(yreg[mt][i]);
    }
    if (wave >= 2) {
        *(uint2*)(&Ys[(32 + er) * 24 + ed]) = make_uint2(pk2bf(epr.x, epr.y), pk2bf(epr.z, epr.w));
        *(float4*)(&ebf[0][ek]) = epr;
        epr = *(const float4*)(eps + (long)1 * 262144 + epsBase);   // prefetch sg=1
    }

    float F1[2][4], F2[2][4], F3[2][4];
    float tracc[2][4] = {{0.f,0.f,0.f,0.f},{0.f,0.f,0.f,0.f}};

    for (int sg = 0; sg < 40; ++sg) {
        const int sub = sg & 3;
        const float ts = 1.0f + DTc * (float)(sg >> 2) + DTc * ((float)sub * (1.0f / 3.0f));
        const short tsb = (short)f2bf(ts);

        __syncthreads();   // B1: Ys/ebf staged

        // ---- layer 1 (K=32; k16 = t slot, k17..31 zero) + GELU -> Xa0 ----
        {
            bf16x8 af[4];
            if (quad < 2) {
                #pragma unroll
                for (int mt = 0; mt < 4; ++mt)
                    af[mt] = *reinterpret_cast<const bf16x8*>(&Ys[(mt * 16 + l15) * 24 + quad * 8]);
            } else {
                #pragma unroll
                for (int mt = 0; mt < 4; ++mt) af[mt] = bf16x8{};
                if (quad == 2) { af[0][0] = tsb; af[1][0] = tsb; }   // fwd rows get t; tangent stay 0
            }
            f32x4 acc[4][3] = {};
            #pragma unroll
            for (int nt = 0; nt < 3; ++nt)
                #pragma unroll
                for (int mt = 0; mt < 4; ++mt)
                    acc[mt][nt] = MFMA16(af[mt], b1yfr[nt], acc[mt][nt]);
            #pragma unroll
            for (int nt = 0; nt < 3; ++nt) {
                int n = (ntg0 + nt) * 16 + l15;
                #pragma unroll
                for (int mt = 0; mt < 2; ++mt) {
                    float gvv[4], dvv[4];
                    #pragma unroll
                    for (int i = 0; i < 4; ++i) {
                        float a = acc[mt][nt][i] + cr[mt][nt][i];
                        float gv, dv; gelu_both(a, gv, dv);
                        gvv[i] = gv; dvv[i] = dv * acc[mt + 2][nt][i];
                    }
                    unsigned int p0 = pk2bf(gvv[0], gvv[1]), p1 = pk2bf(gvv[2], gvv[3]);
                    unsigned int q0 = pk2bf(dvv[0], dvv[1]), q1 = pk2bf(dvv[2], dvv[3]);
                    int ba = (mt * 16 + quad * 4) * 200 + n;
                    Xa0[ba]          = (unsigned short)p0;
                    Xa0[ba + 200]    = (unsigned short)(p0 >> 16);
                    Xa0[ba + 400]    = (unsigned short)p1;
                    Xa0[ba + 600]    = (unsigned short)(p1 >> 16);
                    Xa0[ba + 6400]   = (unsigned short)q0;
                    Xa0[ba + 6600]   = (unsigned short)(q0 >> 16);
                    Xa0[ba + 6800]   = (unsigned short)q1;
                    Xa0[ba + 7000]   = (unsigned short)(q1 >> 16);
                }
            }
        }
        __syncthreads();   // B2: Xa0 ready

        // ---- layer 2 (K=192) -> Xa1 ----
        {
            f32x4 acc2[4][3] = {};
            #pragma unroll
            for (int kb = 0; kb < 6; ++kb) {
                bf16x8 aA[4];
                #pragma unroll
                for (int mt = 0; mt < 4; ++mt)
                    aA[mt] = *reinterpret_cast<const bf16x8*>(&Xa0[(mt * 16 + l15) * 200 + kb * 32 + quad * 8]);
                #pragma unroll
                for (int nt = 0; nt < 3; ++nt) {
                    bf16x8 bf = *reinterpret_cast<const bf16x8*>(w2f + ((kb * 12 + ntg0 + nt) * 64 + lane) * 8);
                    #pragma unroll
                    for (int mt = 0; mt < 4; ++mt)
                        acc2[mt][nt] = MFMA16(aA[mt], bf, acc2[mt][nt]);
                }
            }
            #pragma unroll
            for (int nt = 0; nt < 3; ++nt) {
                int n = (ntg0 + nt) * 16 + l15;
                #pragma unroll
                for (int mt = 0; mt < 2; ++mt) {
                    float gvv[4], dvv[4];
                    #pragma unroll
                    for (int i = 0; i < 4; ++i) {
                        float a = acc2[mt][nt][i] + b2r[nt];
                        float gv, dv; gelu_both(a, gv, dv);
                        gvv[i] = gv; dvv[i] = dv * acc2[mt + 2][nt][i];
                    }
                    unsigned int p0 = pk2bf(gvv[0], gvv[1]), p1 = pk2bf(gvv[2], gvv[3]);
                    unsigned int q0 = pk2bf(dvv[0], dvv[1]), q1 = pk2bf(dvv[2], dvv[3]);
                    int ba = (mt * 16 + quad * 4) * 200 + n;
                    Xa1[ba]          = (unsigned short)p0;
                    Xa1[ba + 200]    = (unsigned short)(p0 >> 16);
                    Xa1[ba + 400]    = (unsigned short)p1;
                    Xa1[ba + 600]    = (unsigned short)(p1 >> 16);
                    Xa1[ba + 6400]   = (unsigned short)q0;
                    Xa1[ba + 6600]   = (unsigned short)(q0 >> 16);
                    Xa1[ba + 6800]   = (unsigned short)q1;
                    Xa1[ba + 7000]   = (unsigned short)(q1 >> 16);
                }
            }
        }
        __syncthreads();   // B3: Xa1 ready

        // ---- layer 3: wave 0 fwd + RK4, wave 1 tangent + trace; waves 2/3 stage eps ----
        if (wave < 2) {
            f32x4 acc3[2] = {};
            #pragma unroll
            for (int kb = 0; kb < 6; ++kb)
                #pragma unroll
                for (int mt = 0; mt < 2; ++mt) {
                    bf16x8 af = *reinterpret_cast<const bf16x8*>(
                        &Xa1[(wave * 32 + mt * 16 + l15) * 200 + kb * 32 + quad * 8]);
                    acc3[mt] = MFMA16(af, w3fr[kb], acc3[mt]);
                }

            if (wave == 0) {
                float Fc[2][4];
                #pragma unroll
                for (int mt = 0; mt < 2; ++mt)
                    #pragma unroll
                    for (int i = 0; i < 4; ++i) Fc[mt][i] = acc3[mt][i] + b3r;
                if (sub == 0) {
                    #pragma unroll
                    for (int mt = 0; mt < 2; ++mt)
                        for (int i = 0; i < 4; ++i) F1[mt][i] = Fc[mt][i];
                } else if (sub == 1) {
                    #pragma unroll
                    for (int mt = 0; mt < 2; ++mt)
                        for (int i = 0; i < 4; ++i) F2[mt][i] = Fc[mt][i];
                } else if (sub == 2) {
                    #pragma unroll
                    for (int mt = 0; mt < 2; ++mt)
                        for (int i = 0; i < 4; ++i) F3[mt][i] = Fc[mt][i];
                } else {
                    #pragma unroll
                    for (int mt = 0; mt < 2; ++mt)
                        #pragma unroll
                        for (int i = 0; i < 4; ++i)
                            yreg[mt][i] += DTc * 0.125f *
                                (F1[mt][i] + 3.0f * (F2[mt][i] + F3[mt][i]) + Fc[mt][i]);
                }
                if (sg < 39) {
                    const int sub2 = (sg + 1) & 3;
                    #pragma unroll
                    for (int mt = 0; mt < 2; ++mt)
                        #pragma unroll
                        for (int i = 0; i < 4; ++i) {
                            float ys = yreg[mt][i];
                            if (sub2 == 1)      ys += DTc * (1.0f / 3.0f) * F1[mt][i];
                            else if (sub2 == 2) ys += DTc * (F2[mt][i] - (1.0f / 3.0f) * F1[mt][i]);
                            else if (sub2 == 3) ys += DTc * (F1[mt][i] - F2[mt][i] + F3[mt][i]);
                            Ys[(mt * 16 + quad * 4 + i) * 24 + l15] = f2bf(ys);
                        }
                }
            } else {
                const float csub = (sub == 1 || sub == 2) ? 3.0f : 1.0f;
                #pragma unroll
                for (int mt = 0; mt < 2; ++mt)
                    #pragma unroll
                    for (int i = 0; i < 4; ++i) {
                        int r = mt * 16 + quad * 4 + i;
                        float p = ebf[sg & 1][r * 16 + l15] * acc3[mt][i];
                        p += __shfl_xor(p, 1);
                        p += __shfl_xor(p, 2);
                        p += __shfl_xor(p, 4);
                        p += __shfl_xor(p, 8);
                        tracc[mt][i] += csub * p;
                    }
            }
        } else {
            if (sg < 39) {
                *(uint2*)(&Ys[(32 + er) * 24 + ed]) = make_uint2(pk2bf(epr.x, epr.y), pk2bf(epr.z, epr.w));
                *(float4*)(&ebf[(sg + 1) & 1][ek]) = epr;
                if (sg < 38)
                    epr = *(const float4*)(eps + (long)(sg + 2) * 262144 + epsBase);
            }
        }
    }

    // ---- combine: trace (wave 1) -> LDS -> output (wave 0) ----
    if (wave == 1 && l15 == 0) {
        #pragma unroll
        for (int mt = 0; mt < 2; ++mt)
            #pragma unroll
            for (int i = 0; i < 4; ++i) trx[mt * 16 + quad * 4 + i] = tracc[mt][i];
    }
    __syncthreads();
    if (wave == 0) {
        #pragma unroll
        for (int mt = 0; mt < 2; ++mt)
            #pragma unroll
            for (int i = 0; i < 4; ++i) {
                float q = yreg[mt][i] * yreg[mt][i];
                q += __shfl_xor(q, 1);
                q += __shfl_xor(q, 2);
                q += __shfl_xor(q, 4);
                q += __shfl_xor(q, 8);
                if (l15 == 0)
                    out[r0 + mt * 16 + quad * 4 + i] =
                        -0.5f * q - 14.7030165313f + DTc * 0.125f * trx[mt * 16 + quad * 4 + i];
            }
    }
}

extern "C" void kernel_launch(void* const* d_in, const int* in_sizes, int n_in,
                              void* d_out, int out_size, void* d_ws, size_t ws_size,
                              hipStream_t stream) {
    const float* theta = (const float*)d_in[0];
    const float* hctx  = (const float*)d_in[1];
    const float* eps   = (const float*)d_in[2];
    const float* W1    = (const float*)d_in[3];
    const float* b1    = (const float*)d_in[4];
    const float* W2    = (const float*)d_in[5];
    const float* b2    = (const float*)d_in[6];
    const float* W3    = (const float*)d_in[7];
    const float* b3    = (const float*)d_in[8];
    float* outp = (float*)d_out;

    unsigned short* w2f  = (unsigned short*)d_ws;   // 36864 elems
    unsigned short* w1yf = w2f + 36864;             // 6144
    unsigned short* w1cf = w1yf + 6144;             // 49152
    unsigned short* w3fg = w1cf + 49152;            // 3072

    hipLaunchKernelGGL(repack_kernel, dim3(47), dim3(256), 0, stream,
                       W1, W2, W3, w2f, w1yf, w1cf, w3fg);
    hipLaunchKernelGGL(cnf_mfma, dim3(512), dim3(256), 0, stream,
                       theta, hctx, eps, b1, b2, b3, w2f, w1yf, w1cf, w3fg, outp);
}

// Round 9
// 347.066 us; speedup vs baseline: 2.3892x; 1.0976x over previous
//
#include <hip/hip_runtime.h>
#include <math.h>

// ConditionalCNF log_prob, MFMA version, round 9.
// Round-8 base (32 rows/block, grid 512 = 2 blocks/CU, 256-reg budget, no spill) +
//  - layer-3 split across ALL 4 waves (wave w: rows w*16+l15; 6 b128 + 6 MFMA each)
//  - RK4 on waves 0/1 (own mt), trace on waves 2/3 as per-lane FMA accumulation,
//    d-reduction deferred to after the stage loop (no per-stage swizzles)
//  - MFMA accumulators seeded with cr / b2 / b3 (no zero-init + add)

#define DTc (-0.1f)

typedef __attribute__((ext_vector_type(8))) short bf16x8;
typedef __attribute__((ext_vector_type(8))) unsigned short u16x8;
typedef __attribute__((ext_vector_type(4))) float f32x4;

#define MFMA16(a, b, c) __builtin_amdgcn_mfma_f32_16x16x32_bf16((a), (b), (c), 0, 0, 0)

__device__ __forceinline__ unsigned short f2bf(float x) {
    union { float f; unsigned int u; } c; c.f = x;
    unsigned int r = c.u + 0x7FFFu + ((c.u >> 16) & 1u);   // RNE
    return (unsigned short)(r >> 16);
}

__device__ __forceinline__ unsigned int pk2bf(float lo, float hi) {
#if __has_builtin(__builtin_amdgcn_cvt_pk_bf16_f32)
    auto v = __builtin_amdgcn_cvt_pk_bf16_f32(lo, hi);     // v_cvt_pk_bf16_f32 (RNE)
    return __builtin_bit_cast(unsigned int, v);
#else
    return (unsigned int)f2bf(lo) | ((unsigned int)f2bf(hi) << 16);
#endif
}

// exact-GELU (erf) + derivative via A&S 7.1.25 3-term rational erf, sharing
// exp(-x^2/2) with the pdf. |erf err| <= 2.5e-5 << bf16 activation rounding.
__device__ __forceinline__ void gelu_both(float x, float& gv, float& dv) {
    float z  = fabsf(x) * 0.70710678118654752f;
    float e  = __builtin_amdgcn_exp2f(x * x * -0.72134752044448170f);  // exp(-x^2/2)
    float t  = __builtin_amdgcn_rcpf(__builtin_fmaf(0.47047f, z, 1.0f));
    float p  = t * (0.1740121f + t * (-0.0479399f + t * 0.3739278f));  // 0.5*(a1 t+a2 t^2+a3 t^3)
    float ch = p * e;                                                  // 0.5*erfc(z)
    float cdf = (x >= 0.0f) ? (1.0f - ch) : ch;
    gv = x * cdf;
    dv = __builtin_fmaf(0.39894228040143268f * x, e, cdf);
}

// ---------------- weight repack: fp32 -> bf16 B-fragments in ws ----------------
// w2f : [kb(6)][nt(12)][lane(64)][8]   B[n][k]=W2[k][n]
// w1yf: [nt(12)][lane(64)][8]          k<16 -> W1[k][n]; k==16 -> W1[272][n]; else 0
// w1cf: [kb(8)][nt(12)][lane(64)][8]   B[n][k]=W1[16+k][n]
// w3f : [kb(6)][lane(64)][8]           B[n][k]=W3[k][n], n=lane&15 (d)
__global__ void repack_kernel(const float* __restrict__ W1, const float* __restrict__ W2,
                              const float* __restrict__ W3,
                              unsigned short* __restrict__ w2f, unsigned short* __restrict__ w1yf,
                              unsigned short* __restrict__ w1cf, unsigned short* __restrict__ w3fg) {
    int t = blockIdx.x * 256 + threadIdx.x;
    u16x8 v;
    if (t < 4608) {
        int kb = t / 768, rem = t % 768, nt = rem / 64, lane = rem % 64;
        int n = nt * 16 + (lane & 15), k0 = kb * 32 + (lane >> 4) * 8;
        #pragma unroll
        for (int j = 0; j < 8; ++j) v[j] = f2bf(W2[(k0 + j) * 192 + n]);
        *(u16x8*)(w2f + t * 8) = v;
    } else if (t < 5376) {
        int i2 = t - 4608, nt = i2 / 64, lane = i2 % 64;
        int n = nt * 16 + (lane & 15), k0 = (lane >> 4) * 8;
        #pragma unroll
        for (int j = 0; j < 8; ++j) {
            int k = k0 + j;
            v[j] = (k < 16) ? f2bf(W1[k * 192 + n])
                 : (k == 16) ? f2bf(W1[272 * 192 + n]) : (unsigned short)0;
        }
        *(u16x8*)(w1yf + i2 * 8) = v;
    } else if (t < 11520) {
        int i3 = t - 5376, kb = i3 / 768, rem = i3 % 768, nt = rem / 64, lane = rem % 64;
        int n = nt * 16 + (lane & 15), k0 = kb * 32 + (lane >> 4) * 8;
        #pragma unroll
        for (int j = 0; j < 8; ++j) v[j] = f2bf(W1[(16 + k0 + j) * 192 + n]);
        *(u16x8*)(w1cf + i3 * 8) = v;
    } else if (t < 11904) {
        int i4 = t - 11520, kb = i4 / 64, lane = i4 % 64;
        int n = lane & 15, k0 = kb * 32 + (lane >> 4) * 8;
        #pragma unroll
        for (int j = 0; j < 8; ++j) v[j] = f2bf(W3[(k0 + j) * 16 + n]);
        *(u16x8*)(w3fg + i4 * 8) = v;
    }
}

// ---------------- main kernel ----------------
__global__ __launch_bounds__(256, 2) void cnf_mfma(
    const float* __restrict__ theta, const float* __restrict__ hctx,
    const float* __restrict__ eps,   const float* __restrict__ b1,
    const float* __restrict__ b2,    const float* __restrict__ b3,
    const unsigned short* __restrict__ w2f, const unsigned short* __restrict__ w1yf,
    const unsigned short* __restrict__ w1cf, const unsigned short* __restrict__ w3fg,
    float* __restrict__ out)
{
    __shared__ __align__(16) unsigned short Ys[64 * 24];   // rows 0-31 y, 32-63 e; k 0..15 only
    __shared__ __align__(16) unsigned short Xa0[64 * 200]; // h1/dh1 (aliased as Hs at init)
    __shared__ __align__(16) unsigned short Xa1[64 * 200]; // h2/dh2
    __shared__ __align__(16) float ebf[2][512];            // fp32 eps, double-buffered
    __shared__ float trx[32];

    const int tid  = threadIdx.x;
    const int wave = tid >> 6, lane = tid & 63;
    const int l15  = lane & 15, quad = lane >> 4;
    const int r0   = blockIdx.x * 32;
    const int ntg0 = wave * 3;
    const int mtw  = wave & 1;      // which fwd m-tile this wave owns in layer 3

    // stage h -> Hs (alias Xa0), stride 264 bf16, float4 global reads
    unsigned short* Hs = Xa0;
    for (int t4 = tid; t4 < 2048; t4 += 256) {
        int r = t4 >> 6, k = (t4 & 63) * 4;
        float4 v = *(const float4*)(hctx + (long)(r0 + r) * 256 + k);
        *(uint2*)(&Hs[r * 264 + k]) = make_uint2(pk2bf(v.x, v.y), pk2bf(v.z, v.w));
    }

    // eps register prefetch (waves 2,3): 4 elems/lane, float4 coalesced
    const int  ek = ((wave - 2) * 64 + lane) * 4;          // 0..508, valid for wave>=2
    const int  er = ek >> 4, ed = ek & 15;
    const long epsBase = (long)r0 * 16 + ek;
    float4 epr;
    if (wave >= 2) epr = *(const float4*)(eps + epsBase);  // sg = 0

    // per-wave constant fragments / scalars
    bf16x8 b1yfr[3], w3fr[6];
    #pragma unroll
    for (int nt = 0; nt < 3; ++nt)
        b1yfr[nt] = *reinterpret_cast<const bf16x8*>(w1yf + ((ntg0 + nt) * 64 + lane) * 8);
    #pragma unroll
    for (int kb = 0; kb < 6; ++kb)
        w3fr[kb] = *reinterpret_cast<const bf16x8*>(w3fg + (kb * 64 + lane) * 8);
    float b2r[3], b1r[3];
    #pragma unroll
    for (int nt = 0; nt < 3; ++nt) {
        int n = (ntg0 + nt) * 16 + l15;
        b2r[nt] = b2[n];
        b1r[nt] = b1[n];
    }
    const float b3r = b3[l15];

    // waves 0,1: integration state for own m-tile: yreg[i] = y[r = mtw*16+quad*4+i][d = l15]
    float yreg[4];
    if (wave < 2) {
        #pragma unroll
        for (int i = 0; i < 4; ++i)
            yreg[i] = theta[(r0 + mtw * 16 + quad * 4 + i) * 16 + l15];
    }

    __syncthreads();   // Hs visible

    // ---- c = b1 + h @ W1ctx, in registers (fwd rows only, mt 0-1) ----
    float cr[2][3][4];
    {
        f32x4 ca[2][3] = {};
        #pragma unroll
        for (int kb = 0; kb < 8; ++kb) {
            bf16x8 af[2];
            #pragma unroll
            for (int mt = 0; mt < 2; ++mt)
                af[mt] = *reinterpret_cast<const bf16x8*>(&Hs[(mt * 16 + l15) * 264 + kb * 32 + quad * 8]);
            #pragma unroll
            for (int nt = 0; nt < 3; ++nt) {
                bf16x8 bf = *reinterpret_cast<const bf16x8*>(w1cf + ((kb * 12 + ntg0 + nt) * 64 + lane) * 8);
                #pragma unroll
                for (int mt = 0; mt < 2; ++mt)
                    ca[mt][nt] = MFMA16(af[mt], bf, ca[mt][nt]);
            }
        }
        #pragma unroll
        for (int mt = 0; mt < 2; ++mt)
            #pragma unroll
            for (int nt = 0; nt < 3; ++nt)
                #pragma unroll
                for (int i = 0; i < 4; ++i)
                    cr[mt][nt][i] = ca[mt][nt][i] + b1r[nt];
    }

    // ---- initial staging for sg=0 ----
    if (wave < 2) {
        #pragma unroll
        for (int i = 0; i < 4; ++i)
            Ys[(mtw * 16 + quad * 4 + i) * 24 + l15] = f2bf(yreg[i]);
    }
    if (wave >= 2) {
        *(uint2*)(&Ys[(32 + er) * 24 + ed]) = make_uint2(pk2bf(epr.x, epr.y), pk2bf(epr.z, epr.w));
        *(float4*)(&ebf[0][ek]) = epr;
        epr = *(const float4*)(eps + (long)1 * 262144 + epsBase);   // prefetch sg=1
    }

    float F1[4], F2[4], F3[4];
    float tracc[4] = {0.f, 0.f, 0.f, 0.f};   // waves 2,3: per-lane (d=l15) trace partials

    for (int sg = 0; sg < 40; ++sg) {
        const int sub = sg & 3;
        const float ts = 1.0f + DTc * (float)(sg >> 2) + DTc * ((float)sub * (1.0f / 3.0f));
        const short tsb = (short)f2bf(ts);

        __syncthreads();   // B1: Ys/ebf staged

        // ---- layer 1 (K=32; k16 = t slot, k17..31 zero) + GELU -> Xa0 ----
        {
            bf16x8 af[4];
            if (quad < 2) {
                #pragma unroll
                for (int mt = 0; mt < 4; ++mt)
                    af[mt] = *reinterpret_cast<const bf16x8*>(&Ys[(mt * 16 + l15) * 24 + quad * 8]);
            } else {
                #pragma unroll
                for (int mt = 0; mt < 4; ++mt) af[mt] = bf16x8{};
                if (quad == 2) { af[0][0] = tsb; af[1][0] = tsb; }   // fwd rows get t; tangent stay 0
            }
            f32x4 acc[4][3];
            #pragma unroll
            for (int nt = 0; nt < 3; ++nt) {
                #pragma unroll
                for (int mt = 0; mt < 2; ++mt)
                    acc[mt][nt] = f32x4{cr[mt][nt][0], cr[mt][nt][1], cr[mt][nt][2], cr[mt][nt][3]};
                acc[2][nt] = f32x4{};
                acc[3][nt] = f32x4{};
            }
            #pragma unroll
            for (int nt = 0; nt < 3; ++nt)
                #pragma unroll
                for (int mt = 0; mt < 4; ++mt)
                    acc[mt][nt] = MFMA16(af[mt], b1yfr[nt], acc[mt][nt]);
            #pragma unroll
            for (int nt = 0; nt < 3; ++nt) {
                int n = (ntg0 + nt) * 16 + l15;
                #pragma unroll
                for (int mt = 0; mt < 2; ++mt) {
                    float gvv[4], dvv[4];
                    #pragma unroll
                    for (int i = 0; i < 4; ++i) {
                        float gv, dv; gelu_both(acc[mt][nt][i], gv, dv);
                        gvv[i] = gv; dvv[i] = dv * acc[mt + 2][nt][i];
                    }
                    unsigned int p0 = pk2bf(gvv[0], gvv[1]), p1 = pk2bf(gvv[2], gvv[3]);
                    unsigned int q0 = pk2bf(dvv[0], dvv[1]), q1 = pk2bf(dvv[2], dvv[3]);
                    int ba = (mt * 16 + quad * 4) * 200 + n;
                    Xa0[ba]          = (unsigned short)p0;
                    Xa0[ba + 200]    = (unsigned short)(p0 >> 16);
                    Xa0[ba + 400]    = (unsigned short)p1;
                    Xa0[ba + 600]    = (unsigned short)(p1 >> 16);
                    Xa0[ba + 6400]   = (unsigned short)q0;
                    Xa0[ba + 6600]   = (unsigned short)(q0 >> 16);
                    Xa0[ba + 6800]   = (unsigned short)q1;
                    Xa0[ba + 7000]   = (unsigned short)(q1 >> 16);
                }
            }
        }
        __syncthreads();   // B2: Xa0 ready

        // ---- layer 2 (K=192) -> Xa1 ----
        {
            f32x4 acc2[4][3];
            #pragma unroll
            for (int nt = 0; nt < 3; ++nt) {
                acc2[0][nt] = f32x4{b2r[nt], b2r[nt], b2r[nt], b2r[nt]};
                acc2[1][nt] = acc2[0][nt];
                acc2[2][nt] = f32x4{};
                acc2[3][nt] = f32x4{};
            }
            #pragma unroll
            for (int kb = 0; kb < 6; ++kb) {
                bf16x8 aA[4];
                #pragma unroll
                for (int mt = 0; mt < 4; ++mt)
                    aA[mt] = *reinterpret_cast<const bf16x8*>(&Xa0[(mt * 16 + l15) * 200 + kb * 32 + quad * 8]);
                #pragma unroll
                for (int nt = 0; nt < 3; ++nt) {
                    bf16x8 bf = *reinterpret_cast<const bf16x8*>(w2f + ((kb * 12 + ntg0 + nt) * 64 + lane) * 8);
                    #pragma unroll
                    for (int mt = 0; mt < 4; ++mt)
                        acc2[mt][nt] = MFMA16(aA[mt], bf, acc2[mt][nt]);
                }
            }
            #pragma unroll
            for (int nt = 0; nt < 3; ++nt) {
                int n = (ntg0 + nt) * 16 + l15;
                #pragma unroll
                for (int mt = 0; mt < 2; ++mt) {
                    float gvv[4], dvv[4];
                    #pragma unroll
                    for (int i = 0; i < 4; ++i) {
                        float gv, dv; gelu_both(acc2[mt][nt][i], gv, dv);
                        gvv[i] = gv; dvv[i] = dv * acc2[mt + 2][nt][i];
                    }
                    unsigned int p0 = pk2bf(gvv[0], gvv[1]), p1 = pk2bf(gvv[2], gvv[3]);
                    unsigned int q0 = pk2bf(dvv[0], dvv[1]), q1 = pk2bf(dvv[2], dvv[3]);
                    int ba = (mt * 16 + quad * 4) * 200 + n;
                    Xa1[ba]          = (unsigned short)p0;
                    Xa1[ba + 200]    = (unsigned short)(p0 >> 16);
                    Xa1[ba + 400]    = (unsigned short)p1;
                    Xa1[ba + 600]    = (unsigned short)(p1 >> 16);
                    Xa1[ba + 6400]   = (unsigned short)q0;
                    Xa1[ba + 6600]   = (unsigned short)(q0 >> 16);
                    Xa1[ba + 6800]   = (unsigned short)q1;
                    Xa1[ba + 7000]   = (unsigned short)(q1 >> 16);
                }
            }
        }
        __syncthreads();   // B3: Xa1 ready

        // ---- layer 3, split 4 ways: wave w owns rows w*16+l15 ----
        {
            f32x4 acc3 = (wave < 2) ? f32x4{b3r, b3r, b3r, b3r} : f32x4{};
            const unsigned short* src = &Xa1[(wave * 16 + l15) * 200];
            #pragma unroll
            for (int kb = 0; kb < 6; ++kb)
                acc3 = MFMA16(*reinterpret_cast<const bf16x8*>(src + kb * 32 + quad * 8), w3fr[kb], acc3);

            if (wave < 2) {
                // forward rows: Fc = acc3 (b3 seeded); RK4 state update + next-y staging
                if (sub == 0) {
                    #pragma unroll
                    for (int i = 0; i < 4; ++i) F1[i] = acc3[i];
                } else if (sub == 1) {
                    #pragma unroll
                    for (int i = 0; i < 4; ++i) F2[i] = acc3[i];
                } else if (sub == 2) {
                    #pragma unroll
                    for (int i = 0; i < 4; ++i) F3[i] = acc3[i];
                } else {
                    #pragma unroll
                    for (int i = 0; i < 4; ++i)
                        yreg[i] += DTc * 0.125f * (F1[i] + 3.0f * (F2[i] + F3[i]) + acc3[i]);
                }
                if (sg < 39) {
                    const int sub2 = (sg + 1) & 3;
                    #pragma unroll
                    for (int i = 0; i < 4; ++i) {
                        float ys = yreg[i];
                        if (sub2 == 1)      ys += DTc * (1.0f / 3.0f) * F1[i];
                        else if (sub2 == 2) ys += DTc * (F2[i] - (1.0f / 3.0f) * F1[i]);
                        else if (sub2 == 3) ys += DTc * (F1[i] - F2[i] + F3[i]);
                        Ys[(mtw * 16 + quad * 4 + i) * 24 + l15] = f2bf(ys);
                    }
                }
            } else {
                // tangent rows: per-lane trace partial (d = l15), reduced after the loop
                const float csub = (sub == 1 || sub == 2) ? 3.0f : 1.0f;
                #pragma unroll
                for (int i = 0; i < 4; ++i) {
                    int r = mtw * 16 + quad * 4 + i;
                    tracc[i] = __builtin_fmaf(csub * ebf[sg & 1][r * 16 + l15], acc3[i], tracc[i]);
                }
                // stage next eps
                if (sg < 39) {
                    *(uint2*)(&Ys[(32 + er) * 24 + ed]) = make_uint2(pk2bf(epr.x, epr.y), pk2bf(epr.z, epr.w));
                    *(float4*)(&ebf[(sg + 1) & 1][ek]) = epr;
                    if (sg < 38)
                        epr = *(const float4*)(eps + (long)(sg + 2) * 262144 + epsBase);
                }
            }
        }
    }

    // ---- final trace reduction (waves 2,3) -> trx ----
    if (wave >= 2) {
        #pragma unroll
        for (int i = 0; i < 4; ++i) {
            float v = tracc[i];
            v += __shfl_xor(v, 1);
            v += __shfl_xor(v, 2);
            v += __shfl_xor(v, 4);
            v += __shfl_xor(v, 8);
            if (l15 == 0) trx[mtw * 16 + quad * 4 + i] = v;
        }
    }
    __syncthreads();

    // ---- output (waves 0,1 hold final y for their m-tile) ----
    if (wave < 2) {
        #pragma unroll
        for (int i = 0; i < 4; ++i) {
            float q = yreg[i] * yreg[i];
            q += __shfl_xor(q, 1);
            q += __shfl_xor(q, 2);
            q += __shfl_xor(q, 4);
            q += __shfl_xor(q, 8);
            if (l15 == 0) {
                int r = mtw * 16 + quad * 4 + i;
                out[r0 + r] = -0.5f * q - 14.7030165313f + DTc * 0.125f * trx[r];
            }
        }
    }
}

extern "C" void kernel_launch(void* const* d_in, const int* in_sizes, int n_in,
                              void* d_out, int out_size, void* d_ws, size_t ws_size,
                              hipStream_t stream) {
    const float* theta = (const float*)d_in[0];
    const float* hctx  = (const float*)d_in[1];
    const float* eps   = (const float*)d_in[2];
    const float* W1    = (const float*)d_in[3];
    const float* b1    = (const float*)d_in[4];
    const float* W2    = (const float*)d_in[5];
    const float* b2    = (const float*)d_in[6];
    const float* W3    = (const float*)d_in[7];
    const float* b3    = (const float*)d_in[8];
    float* outp = (float*)d_out;

    unsigned short* w2f  = (unsigned short*)d_ws;   // 36864 elems
    unsigned short* w1yf = w2f + 36864;             // 6144
    unsigned short* w1cf = w1yf + 6144;             // 49152
    unsigned short* w3fg = w1cf + 49152;            // 3072

    hipLaunchKernelGGL(repack_kernel, dim3(47), dim3(256), 0, stream,
                       W1, W2, W3, w2f, w1yf, w1cf, w3fg);
    hipLaunchKernelGGL(cnf_mfma, dim3(512), dim3(256), 0, stream,
                       theta, hctx, eps, b1, b2, b3, w2f, w1yf, w1cf, w3fg, outp);
}